// Round 5
// baseline (412.154 us; speedup 1.0000x reference)
//
#include <hip/hip_runtime.h>
#include <math.h>

#define NHID  1024
#define NCLS  224
#define NTPC  225
#define BATCH 2048

#define NBOT_BLOCKS (NCLS * 4)      // class c, K-chunk k (256 rows each)
#define NTOP_BLOCKS (128 * 4)       // sample-tile st, K-chunk k

// ws layout (bytes):
#define CLS_OFF  0
#define POS_OFF  8192
#define LIST_OFF 16384
#define OFFS_OFF 24576
#define YTOP_OFF 32768
#define YTOP_BYTES (BATCH * NCLS * 4)
#define YBOT_OFF (YTOP_OFF + YTOP_BYTES)
#define YBOT_BYTES (BATCH * NTPC * 4)

// ---------------------------------------------------------------------------
// Pass 0: label decode (int32/int64 autodetect), class/pos, group-by-class.
// ---------------------------------------------------------------------------
__global__ __launch_bounds__(256) void group_kernel(const int* __restrict__ labels,
                                                    int* __restrict__ cls,
                                                    int* __restrict__ pos,
                                                    int* __restrict__ list,
                                                    int* __restrict__ offs) {
    __shared__ int cnt[NCLS];
    __shared__ int sc[256];
    __shared__ int bex[NCLS];
    __shared__ int nz;
    const int tid = threadIdx.x;
    if (tid == 0) nz = 0;
    for (int j = tid; j < NCLS; j += 256) cnt[j] = 0;
    __syncthreads();
    int loc = 0;
    for (int k = 0; k < 4; ++k) {
        int i = tid + 256 * k;
        if (labels[2 * i + 1] != 0) loc = 1;
    }
    if (loc) atomicOr(&nz, 1);
    __syncthreads();
    const bool is64 = (nz == 0);
    int myc[8], myr[8];
#pragma unroll
    for (int k = 0; k < 8; ++k) {
        int i = tid + 256 * k;
        int l = is64 ? labels[2 * i] : labels[i];
        int c = l / NTPC;
        cls[i] = c;
        pos[i] = l - c * NTPC;
        myc[k] = c;
        myr[k] = atomicAdd(&cnt[c], 1);
    }
    __syncthreads();
    int v = (tid < NCLS) ? cnt[tid] : 0;
    sc[tid] = v;
    __syncthreads();
    for (int off = 1; off < 256; off <<= 1) {
        int u = (tid >= off) ? sc[tid - off] : 0;
        __syncthreads();
        sc[tid] += u;
        __syncthreads();
    }
    if (tid < NCLS) {
        int ex = sc[tid] - v;
        bex[tid] = ex;
        offs[tid] = ex;
    }
    if (tid == 0) offs[NCLS] = BATCH;
    __syncthreads();
#pragma unroll
    for (int k = 0; k < 8; ++k) {
        int i = tid + 256 * k;
        list[bex[myc[k]] + myr[k]] = i;
    }
}

// ---------------------------------------------------------------------------
// Pass 1 (fused): K-split partial GEMMs. 256 threads = 4 waves.
// Block = (class|sample-tile) x K-chunk of 256 rows. WITHIN the block, the
// 4 waves split K again: wave w owns rows 64w..64w+63 and covers ALL columns,
// lane l -> cols {l, 64+l, 128+l, 192+l}. One ds_read_b128 (4 samples) feeds
// 16 FMAs => 1 B LDS-return per FMA (LDS pipe no longer 4x oversubscribed).
// W read once per block: 4 coalesced dword loads per wave-iteration.
// NQ = number of active 4-sample quads, templated to trim padded-FMA waste.
// Partials accumulated into global y via atomicAdd (4 K-chunk blocks collide).
// ---------------------------------------------------------------------------
template <int NQ>
__device__ __forceinline__ void pk_compute(const float* __restrict__ wr0,
                                           const float* __restrict__ xs,
                                           float acc[NQ][4][4],
                                           int ycols, int hw, int l) {
#pragma unroll
    for (int q = 0; q < NQ; ++q)
#pragma unroll
        for (int m = 0; m < 4; ++m)
#pragma unroll
            for (int g = 0; g < 4; ++g) acc[q][m][g] = 0.f;
    const float* wr = wr0;
#pragma unroll 4
    for (int h = 0; h < 64; ++h) {
        const int hh = hw + h;
        float wv[4];
        wv[0] = wr[0];
        wv[1] = wr[64];
        wv[2] = wr[128];
        wv[3] = wr[192 + l < ycols ? 192 : 0];   // clamp: garbage ok, never stored
        const int sw = (hh >> 1) & 3;
#pragma unroll
        for (int q = 0; q < NQ; ++q) {
            float4 xq = *(const float4*)&xs[(hh << 4) + 4 * (q ^ sw)];
            const float xm[4] = {xq.x, xq.y, xq.z, xq.w};
#pragma unroll
            for (int m = 0; m < 4; ++m)
#pragma unroll
                for (int g = 0; g < 4; ++g)
                    acc[q][m][g] = fmaf(xm[m], wv[g], acc[q][m][g]);
        }
        wr += ycols;
    }
}

__global__ __launch_bounds__(256, 4) void partial_kernel(const float* __restrict__ x,
                                                         const float* __restrict__ Wt,
                                                         const float* __restrict__ Wb,
                                                         const int* __restrict__ list,
                                                         const int* __restrict__ offs,
                                                         float* __restrict__ ytop,
                                                         float* __restrict__ ybot) {
    __shared__ __align__(16) float xs[256 * 16];   // 16 KB
    const int tid = threadIdx.x;
    const int w = tid >> 6, l = tid & 63;
    const int bi = blockIdx.x;
    const bool isBot = (bi < NBOT_BLOCKS);

    int k, o, n, ycols;
    const float* W;
    float* y;
    if (isBot) {
        int c = bi >> 2; k = bi & 3;
        o = offs[c]; n = offs[c + 1] - o;
        W = Wb + (size_t)c * (NHID * NTPC);
        y = ybot; ycols = NTPC;
    } else {
        int b2 = bi - NBOT_BLOCKS;
        int st = b2 >> 2; k = b2 & 3;
        o = st * 16; n = 16;
        W = Wt; y = ytop; ycols = NCLS;
    }
    const int hbase = k * 256;
    const int hw = 64 * w;                 // this wave's row offset in the chunk
    const int hq = (tid >> 1) & 3;         // staging swizzle key (row = tid)
    const float* wr0 = W + (size_t)(hbase + hw) * ycols + l;

    for (int tile = 0; tile * 16 < n; ++tile) {
        if (tile) __syncthreads();
        // stage: thread tid stages row tid of the chunk for 16 tile samples
        const float* xcol = x + hbase + tid;
#pragma unroll
        for (int i = 0; i < 16; ++i) {
            int idx = tile * 16 + i;
            int s = isBot ? list[o + min(idx, n - 1)] : (o + i);
            xs[(tid << 4) + ((((i >> 2) ^ hq) << 2) | (i & 3))] = xcol[(size_t)s * NHID];
        }
        __syncthreads();

        const int nt = min(n - tile * 16, 16);
        const int nq = (nt + 3) >> 2;
        float acc[4][4][4];
        switch (nq) {
            case 1: pk_compute<1>(wr0, xs, (float(*)[4][4])acc, ycols, hw, l); break;
            case 2: pk_compute<2>(wr0, xs, (float(*)[4][4])acc, ycols, hw, l); break;
            case 3: pk_compute<3>(wr0, xs, (float(*)[4][4])acc, ycols, hw, l); break;
            default: pk_compute<4>(wr0, xs, (float(*)[4][4])acc, ycols, hw, l); break;
        }

        for (int q = 0; q < nq; ++q) {
#pragma unroll
            for (int m = 0; m < 4; ++m) {
                int idx = tile * 16 + 4 * q + m;
                if (idx < n) {
                    int s = isBot ? list[o + idx] : (o + idx);
                    float* yr = y + (size_t)s * ycols;
                    atomicAdd(&yr[l], acc[q][m][0]);
                    atomicAdd(&yr[l + 64], acc[q][m][1]);
                    atomicAdd(&yr[l + 128], acc[q][m][2]);
                    if (l + 192 < ycols) atomicAdd(&yr[l + 192], acc[q][m][3]);
                }
            }
        }
    }
}

// ---------------------------------------------------------------------------
// Pass 2: per-sample dual softmax + product. One wave per sample.
// ---------------------------------------------------------------------------
__global__ __launch_bounds__(256) void finalize_kernel(const float* __restrict__ ytop,
                                                       const float* __restrict__ ybot,
                                                       const float* __restrict__ bt,
                                                       const float* __restrict__ bb,
                                                       const int* __restrict__ cls,
                                                       const int* __restrict__ pos,
                                                       float* __restrict__ out) {
    const int w = threadIdx.x >> 6, l = threadIdx.x & 63;
    const int s = blockIdx.x * 4 + w;
    const int c = cls[s], p = pos[s];

    float v[4];
#pragma unroll
    for (int g = 0; g < 4; ++g) {
        int col = l + 64 * g;
        v[g] = (col < NCLS) ? ytop[(size_t)s * NCLS + col] + bt[col] : -INFINITY;
    }
    float mx = fmaxf(fmaxf(v[0], v[1]), fmaxf(v[2], v[3]));
#pragma unroll
    for (int off = 32; off; off >>= 1) mx = fmaxf(mx, __shfl_xor(mx, off));
    float sum = 0.f, tc = 0.f;
#pragma unroll
    for (int g = 0; g < 4; ++g) {
        int col = l + 64 * g;
        float e = (col < NCLS) ? __expf(v[g] - mx) : 0.f;
        sum += e;
        if (col == c) tc = e;
    }
#pragma unroll
    for (int off = 32; off; off >>= 1) {
        sum += __shfl_xor(sum, off);
        tc  += __shfl_xor(tc, off);
    }
    const float tp = tc / sum;

#pragma unroll
    for (int g = 0; g < 4; ++g) {
        int col = l + 64 * g;
        v[g] = (col < NTPC) ? ybot[(size_t)s * NTPC + col] + bb[c * NTPC + col] : -INFINITY;
    }
    mx = fmaxf(fmaxf(v[0], v[1]), fmaxf(v[2], v[3]));
#pragma unroll
    for (int off = 32; off; off >>= 1) mx = fmaxf(mx, __shfl_xor(mx, off));
    float bsum = 0.f, ep = 0.f;
#pragma unroll
    for (int g = 0; g < 4; ++g) {
        int col = l + 64 * g;
        float e = (col < NTPC) ? __expf(v[g] - mx) : 0.f;
        bsum += e;
        if (col == p) ep = e;
    }
#pragma unroll
    for (int off = 32; off; off >>= 1) bsum += __shfl_xor(bsum, off);
#pragma unroll
    for (int g = 0; g < 4; ++g)
        if (l + 64 * g == p) out[s] = tp * ep / bsum;
}

extern "C" void kernel_launch(void* const* d_in, const int* in_sizes, int n_in,
                              void* d_out, int out_size, void* d_ws, size_t ws_size,
                              hipStream_t stream) {
    const float* inputs = (const float*)d_in[0];
    const int*   labels = (const int*)d_in[1];
    const float* topW   = (const float*)d_in[2];
    const float* topB   = (const float*)d_in[3];
    const float* botW   = (const float*)d_in[4];
    const float* botB   = (const float*)d_in[5];
    float* out = (float*)d_out;

    char* ws   = (char*)d_ws;
    int*   cls = (int*)(ws + CLS_OFF);
    int*   pos = (int*)(ws + POS_OFF);
    int*   lst = (int*)(ws + LIST_OFF);
    int*   off = (int*)(ws + OFFS_OFF);
    float* ytop = (float*)(ws + YTOP_OFF);
    float* ybot = (float*)(ws + YBOT_OFF);

    hipMemsetAsync(ws + YTOP_OFF, 0, YTOP_BYTES + YBOT_BYTES, stream);
    group_kernel<<<1, 256, 0, stream>>>(labels, cls, pos, lst, off);
    partial_kernel<<<NBOT_BLOCKS + NTOP_BLOCKS, 256, 0, stream>>>(
        inputs, topW, botW, lst, off, ytop, ybot);
    finalize_kernel<<<BATCH / 4, 256, 0, stream>>>(ytop, ybot, topB, botB, cls, pos, out);
}